// Round 1
// baseline (762.576 us; speedup 1.0000x reference)
//
#include <hip/hip_runtime.h>

#define Bv 8
#define Cv 256
#define Hv 128
#define Wv 128
#define HWv (Hv * Wv)
#define Gv 1024
#define Pv 1024

// NCHW -> NHWC transpose: in[b][c][hw] -> out[b][hw][c]
__global__ __launch_bounds__(256) void transpose_k(const float* __restrict__ in,
                                                   float* __restrict__ out) {
    __shared__ float tile[32][33];
    int b  = blockIdx.z;
    int c0 = blockIdx.y * 32;
    int s0 = blockIdx.x * 32;
    int tx = threadIdx.x;  // 0..31
    int ty = threadIdx.y;  // 0..7
    const float* ip = in + ((size_t)b * Cv + c0) * HWv + s0;
#pragma unroll
    for (int i = 0; i < 32; i += 8)
        tile[ty + i][tx] = ip[(size_t)(ty + i) * HWv + tx];
    __syncthreads();
    float* op = out + ((size_t)b * HWv + s0) * Cv + c0;
#pragma unroll
    for (int i = 0; i < 32; i += 8)
        op[(size_t)(ty + i) * Cv + tx] = tile[tx][ty + i];
}

// One 64-lane wave per sample point; each lane handles 4 channels (float4).
__global__ __launch_bounds__(256) void sample_nhwc_k(const float* __restrict__ map,
                                                     const float* __restrict__ pts,
                                                     const int* __restrict__ bids,
                                                     float* __restrict__ out) {
    int t    = blockIdx.x * 256 + threadIdx.x;
    int pt   = t >> 6;        // point index in [0, G*P)
    int lane = t & 63;
    int g    = pt >> 10;      // P = 1024

    float px = pts[2 * (size_t)pt + 0];
    float py = pts[2 * (size_t)pt + 1];
    int   b  = bids[g];

    // x = (2p-1+1)*(W/2) - 0.5 = W*p - 0.5
    float x = (float)Wv * px - 0.5f;
    float y = (float)Hv * py - 0.5f;
    float x0f = floorf(x), y0f = floorf(y);
    float wx = x - x0f, wy = y - y0f;
    int x0 = (int)x0f, y0 = (int)y0f;
    int x1 = x0 + 1,   y1 = y0 + 1;

    bool vx0 = (x0 >= 0) & (x0 < Wv);
    bool vx1 = (x1 >= 0) & (x1 < Wv);
    bool vy0 = (y0 >= 0) & (y0 < Hv);
    bool vy1 = (y1 >= 0) & (y1 < Hv);
    int xc0 = min(max(x0, 0), Wv - 1);
    int xc1 = min(max(x1, 0), Wv - 1);
    int yc0 = min(max(y0, 0), Hv - 1);
    int yc1 = min(max(y1, 0), Hv - 1);

    // fold validity into the weights
    float w00 = (1.0f - wx) * (1.0f - wy) * ((vx0 & vy0) ? 1.0f : 0.0f);
    float w01 = wx * (1.0f - wy)          * ((vx1 & vy0) ? 1.0f : 0.0f);
    float w10 = (1.0f - wx) * wy          * ((vx0 & vy1) ? 1.0f : 0.0f);
    float w11 = wx * wy                   * ((vx1 & vy1) ? 1.0f : 0.0f);

    size_t bbase = (size_t)b * HWv * Cv;
    const float4* p00 = (const float4*)(map + bbase + ((size_t)yc0 * Wv + xc0) * Cv) + lane;
    const float4* p01 = (const float4*)(map + bbase + ((size_t)yc0 * Wv + xc1) * Cv) + lane;
    const float4* p10 = (const float4*)(map + bbase + ((size_t)yc1 * Wv + xc0) * Cv) + lane;
    const float4* p11 = (const float4*)(map + bbase + ((size_t)yc1 * Wv + xc1) * Cv) + lane;

    float4 v00 = *p00;
    float4 v01 = *p01;
    float4 v10 = *p10;
    float4 v11 = *p11;

    float4 r;
    r.x = v00.x * w00 + v01.x * w01 + v10.x * w10 + v11.x * w11;
    r.y = v00.y * w00 + v01.y * w01 + v10.y * w10 + v11.y * w11;
    r.z = v00.z * w00 + v01.z * w01 + v10.z * w10 + v11.z * w11;
    r.w = v00.w * w00 + v01.w * w01 + v10.w * w10 + v11.w * w11;

    ((float4*)(out + (size_t)pt * Cv))[lane] = r;
}

// Fallback: direct NCHW gather (uncoalesced, correctness-only path).
__global__ __launch_bounds__(256) void sample_nchw_k(const float* __restrict__ map,
                                                     const float* __restrict__ pts,
                                                     const int* __restrict__ bids,
                                                     float* __restrict__ out) {
    int t    = blockIdx.x * 256 + threadIdx.x;
    int pt   = t >> 6;
    int lane = t & 63;
    int g    = pt >> 10;

    float px = pts[2 * (size_t)pt + 0];
    float py = pts[2 * (size_t)pt + 1];
    int   b  = bids[g];

    float x = (float)Wv * px - 0.5f;
    float y = (float)Hv * py - 0.5f;
    float x0f = floorf(x), y0f = floorf(y);
    float wx = x - x0f, wy = y - y0f;
    int x0 = (int)x0f, y0 = (int)y0f;
    int x1 = x0 + 1,   y1 = y0 + 1;

    bool vx0 = (x0 >= 0) & (x0 < Wv);
    bool vx1 = (x1 >= 0) & (x1 < Wv);
    bool vy0 = (y0 >= 0) & (y0 < Hv);
    bool vy1 = (y1 >= 0) & (y1 < Hv);
    int xc0 = min(max(x0, 0), Wv - 1);
    int xc1 = min(max(x1, 0), Wv - 1);
    int yc0 = min(max(y0, 0), Hv - 1);
    int yc1 = min(max(y1, 0), Hv - 1);

    float w00 = (1.0f - wx) * (1.0f - wy) * ((vx0 & vy0) ? 1.0f : 0.0f);
    float w01 = wx * (1.0f - wy)          * ((vx1 & vy0) ? 1.0f : 0.0f);
    float w10 = (1.0f - wx) * wy          * ((vx0 & vy1) ? 1.0f : 0.0f);
    float w11 = wx * wy                   * ((vx1 & vy1) ? 1.0f : 0.0f);

    int c = lane * 4;
    const float* base = map + ((size_t)b * Cv + c) * HWv;
    size_t o00 = (size_t)yc0 * Wv + xc0;
    size_t o01 = (size_t)yc0 * Wv + xc1;
    size_t o10 = (size_t)yc1 * Wv + xc0;
    size_t o11 = (size_t)yc1 * Wv + xc1;

    float4 r;
    float* rp = (float*)&r;
#pragma unroll
    for (int j = 0; j < 4; ++j) {
        const float* ch = base + (size_t)j * HWv;
        rp[j] = ch[o00] * w00 + ch[o01] * w01 + ch[o10] * w10 + ch[o11] * w11;
    }
    ((float4*)(out + (size_t)pt * Cv))[lane] = r;
}

extern "C" void kernel_launch(void* const* d_in, const int* in_sizes, int n_in,
                              void* d_out, int out_size, void* d_ws, size_t ws_size,
                              hipStream_t stream) {
    const float* map  = (const float*)d_in[0];
    const float* pts  = (const float*)d_in[1];
    const int*   bids = (const int*)d_in[2];
    float*       out  = (float*)d_out;

    size_t map_bytes = (size_t)Bv * Cv * Hv * Wv * sizeof(float);
    int npts = Gv * Pv;
    int nthreads = npts * 64;           // one wave per point
    int nblocks = nthreads / 256;

    if (ws_size >= map_bytes) {
        float* nhwc = (float*)d_ws;
        dim3 tb(32, 8);
        dim3 tg(HWv / 32, Cv / 32, Bv);
        transpose_k<<<tg, tb, 0, stream>>>(map, nhwc);
        sample_nhwc_k<<<nblocks, 256, 0, stream>>>(nhwc, pts, bids, out);
    } else {
        sample_nchw_k<<<nblocks, 256, 0, stream>>>(map, pts, bids, out);
    }
}

// Round 3
// 447.349 us; speedup vs baseline: 1.7047x; 1.7047x over previous
//
#include <hip/hip_runtime.h>

#define Bv 8
#define Cv 256
#define Hv 128
#define Wv 128
#define HWv (Hv * Wv)
#define Gv 1024
#define Pv 1024

typedef __attribute__((ext_vector_type(4))) _Float16 half4;
typedef __attribute__((ext_vector_type(4))) float f32x4;

// NCHW fp32 -> NHWC fp16: in[b][c][hw] -> out[b][hw][c]
// Block handles 32 spatial x 64 channels.
__global__ __launch_bounds__(256) void transpose_h_k(const float* __restrict__ in,
                                                     _Float16* __restrict__ out) {
    __shared__ float tile[64][33];
    int b  = blockIdx.z;
    int c0 = blockIdx.y * 64;
    int s0 = blockIdx.x * 32;
    int lin = threadIdx.x;          // 0..255
    int tx  = lin & 31;
    int ty  = lin >> 5;             // 0..7

    const float* ip = in + ((size_t)(b * Cv + c0 + ty)) * HWv + s0 + tx;
#pragma unroll
    for (int i = 0; i < 64; i += 8)
        tile[ty + i][tx] = ip[(size_t)i * HWv];
    __syncthreads();

    // write 32 rows; each row = 64 fp16 = 32 uints; 8 rows per iteration
    int cp = lin & 31;              // channel pair 0..31
    int r8 = lin >> 5;              // 0..7
#pragma unroll
    for (int it = 0; it < 4; ++it) {
        int r = r8 + it * 8;
        union { _Float16 h[2]; unsigned u; } pk;
        pk.h[0] = (_Float16)tile[2 * cp + 0][r];
        pk.h[1] = (_Float16)tile[2 * cp + 1][r];
        unsigned* dst = (unsigned*)(out + ((size_t)b * HWv + s0 + r) * Cv + c0);
        dst[cp] = pk.u;
    }
}

__device__ __forceinline__ void point_setup(const float* __restrict__ pts,
                                            const int* __restrict__ bids, int pt,
                                            size_t& o00, size_t& o01, size_t& o10, size_t& o11,
                                            float& w00, float& w01, float& w10, float& w11) {
    int g = pt >> 10;               // P = 1024
    float px = pts[2 * (size_t)pt + 0];
    float py = pts[2 * (size_t)pt + 1];
    int b = bids[g];

    float x = (float)Wv * px - 0.5f;
    float y = (float)Hv * py - 0.5f;
    float x0f = floorf(x), y0f = floorf(y);
    float wx = x - x0f, wy = y - y0f;
    int x0 = (int)x0f, y0 = (int)y0f;
    int x1 = x0 + 1,   y1 = y0 + 1;

    bool vx0 = (unsigned)x0 < (unsigned)Wv;
    bool vx1 = (unsigned)x1 < (unsigned)Wv;
    bool vy0 = (unsigned)y0 < (unsigned)Hv;
    bool vy1 = (unsigned)y1 < (unsigned)Hv;
    int xc0 = min(max(x0, 0), Wv - 1);
    int xc1 = min(max(x1, 0), Wv - 1);
    int yc0 = min(max(y0, 0), Hv - 1);
    int yc1 = min(max(y1, 0), Hv - 1);

    w00 = (1.0f - wx) * (1.0f - wy) * ((vx0 & vy0) ? 1.0f : 0.0f);
    w01 = wx * (1.0f - wy)          * ((vx1 & vy0) ? 1.0f : 0.0f);
    w10 = (1.0f - wx) * wy          * ((vx0 & vy1) ? 1.0f : 0.0f);
    w11 = wx * wy                   * ((vx1 & vy1) ? 1.0f : 0.0f);

    size_t bbase = (size_t)b * HWv * Cv;
    o00 = bbase + ((size_t)yc0 * Wv + xc0) * Cv;
    o01 = bbase + ((size_t)yc0 * Wv + xc1) * Cv;
    o10 = bbase + ((size_t)yc1 * Wv + xc0) * Cv;
    o11 = bbase + ((size_t)yc1 * Wv + xc1) * Cv;
}

__device__ __forceinline__ f32x4 blend(half4 v00, half4 v01, half4 v10, half4 v11,
                                       float w00, float w01, float w10, float w11) {
    f32x4 r;
    r.x = (float)v00.x * w00 + (float)v01.x * w01 + (float)v10.x * w10 + (float)v11.x * w11;
    r.y = (float)v00.y * w00 + (float)v01.y * w01 + (float)v10.y * w10 + (float)v11.y * w11;
    r.z = (float)v00.z * w00 + (float)v01.z * w01 + (float)v10.z * w10 + (float)v11.z * w11;
    r.w = (float)v00.w * w00 + (float)v01.w * w01 + (float)v10.w * w10 + (float)v11.w * w11;
    return r;
}

// One 64-lane wave per TWO sample points; each lane handles 4 channels.
// All 8 corner loads issued before any use (MLP).
__global__ __launch_bounds__(256) void sample_nhwc_h_k(const _Float16* __restrict__ map,
                                                       const float* __restrict__ pts,
                                                       const int* __restrict__ bids,
                                                       float* __restrict__ out) {
    int t    = blockIdx.x * 256 + threadIdx.x;
    int wave = t >> 6;
    int lane = t & 63;
    int pt0  = wave * 2;
    int pt1  = pt0 + 1;

    size_t a00, a01, a10, a11, b00, b01, b10, b11;
    float wa00, wa01, wa10, wa11, wb00, wb01, wb10, wb11;
    point_setup(pts, bids, pt0, a00, a01, a10, a11, wa00, wa01, wa10, wa11);
    point_setup(pts, bids, pt1, b00, b01, b10, b11, wb00, wb01, wb10, wb11);

    size_t cl = (size_t)lane * 4;   // channel offset (4 halves = 8 bytes)
    half4 va00 = *(const half4*)(map + a00 + cl);
    half4 va01 = *(const half4*)(map + a01 + cl);
    half4 va10 = *(const half4*)(map + a10 + cl);
    half4 va11 = *(const half4*)(map + a11 + cl);
    half4 vb00 = *(const half4*)(map + b00 + cl);
    half4 vb01 = *(const half4*)(map + b01 + cl);
    half4 vb10 = *(const half4*)(map + b10 + cl);
    half4 vb11 = *(const half4*)(map + b11 + cl);

    f32x4 r0 = blend(va00, va01, va10, va11, wa00, wa01, wa10, wa11);
    f32x4 r1 = blend(vb00, vb01, vb10, vb11, wb00, wb01, wb10, wb11);

    __builtin_nontemporal_store(r0, (f32x4*)(out + (size_t)pt0 * Cv) + lane);
    __builtin_nontemporal_store(r1, (f32x4*)(out + (size_t)pt1 * Cv) + lane);
}

// Fallback: direct NCHW fp32 gather (correctness-only path).
__global__ __launch_bounds__(256) void sample_nchw_k(const float* __restrict__ map,
                                                     const float* __restrict__ pts,
                                                     const int* __restrict__ bids,
                                                     float* __restrict__ out) {
    int t    = blockIdx.x * 256 + threadIdx.x;
    int pt   = t >> 6;
    int lane = t & 63;

    int g = pt >> 10;
    float px = pts[2 * (size_t)pt + 0];
    float py = pts[2 * (size_t)pt + 1];
    int b = bids[g];
    float x = (float)Wv * px - 0.5f;
    float y = (float)Hv * py - 0.5f;
    float x0f = floorf(x), y0f = floorf(y);
    float wx = x - x0f, wy = y - y0f;
    int x0 = (int)x0f, y0 = (int)y0f;
    int x1 = x0 + 1,   y1 = y0 + 1;
    bool vx0 = (unsigned)x0 < (unsigned)Wv;
    bool vx1 = (unsigned)x1 < (unsigned)Wv;
    bool vy0 = (unsigned)y0 < (unsigned)Hv;
    bool vy1 = (unsigned)y1 < (unsigned)Hv;
    int xc0 = min(max(x0, 0), Wv - 1);
    int xc1 = min(max(x1, 0), Wv - 1);
    int yc0 = min(max(y0, 0), Hv - 1);
    int yc1 = min(max(y1, 0), Hv - 1);
    float w00 = (1.0f - wx) * (1.0f - wy) * ((vx0 & vy0) ? 1.0f : 0.0f);
    float w01 = wx * (1.0f - wy)          * ((vx1 & vy0) ? 1.0f : 0.0f);
    float w10 = (1.0f - wx) * wy          * ((vx0 & vy1) ? 1.0f : 0.0f);
    float w11 = wx * wy                   * ((vx1 & vy1) ? 1.0f : 0.0f);

    int c = lane * 4;
    const float* base = map + ((size_t)b * Cv + c) * HWv;
    size_t s00 = (size_t)yc0 * Wv + xc0;
    size_t s01 = (size_t)yc0 * Wv + xc1;
    size_t s10 = (size_t)yc1 * Wv + xc0;
    size_t s11 = (size_t)yc1 * Wv + xc1;

    f32x4 r;
#pragma unroll
    for (int j = 0; j < 4; ++j) {
        const float* ch = base + (size_t)j * HWv;
        r[j] = ch[s00] * w00 + ch[s01] * w01 + ch[s10] * w10 + ch[s11] * w11;
    }
    *((f32x4*)(out + (size_t)pt * Cv) + lane) = r;
}

extern "C" void kernel_launch(void* const* d_in, const int* in_sizes, int n_in,
                              void* d_out, int out_size, void* d_ws, size_t ws_size,
                              hipStream_t stream) {
    const float* map  = (const float*)d_in[0];
    const float* pts  = (const float*)d_in[1];
    const int*   bids = (const int*)d_in[2];
    float*       out  = (float*)d_out;

    size_t map_h_bytes = (size_t)Bv * Cv * Hv * Wv * sizeof(_Float16);
    int npts = Gv * Pv;

    if (ws_size >= map_h_bytes) {
        _Float16* nhwc = (_Float16*)d_ws;
        dim3 tb(256);
        dim3 tg(HWv / 32, Cv / 64, Bv);
        transpose_h_k<<<tg, tb, 0, stream>>>(map, nhwc);
        int nwaves  = npts / 2;                 // 2 points per wave
        int nblocks = nwaves * 64 / 256;
        sample_nhwc_h_k<<<nblocks, 256, 0, stream>>>(nhwc, pts, bids, out);
    } else {
        int nblocks = npts * 64 / 256;
        sample_nchw_k<<<nblocks, 256, 0, stream>>>(map, pts, bids, out);
    }
}

// Round 4
// 306.961 us; speedup vs baseline: 2.4843x; 1.4573x over previous
//
#include <hip/hip_runtime.h>

#define Bv 8
#define Cv 256
#define Hv 128
#define Wv 128
#define HWv (Hv * Wv)
#define Gv 1024
#define Pv 1024

typedef __attribute__((ext_vector_type(4))) _Float16 half4;
typedef __attribute__((ext_vector_type(4))) float f32x4;

// d_ws layout:
//   [0, 4K)   : meta ints: perm[1024] | cnt[8] | off[8] | cum[9]
//   [8K, ...) : fp16 NHWC map (B*HW*C halves = 67 MB)
#define META_INTS (1024 + 8 + 8 + 9)
#define MAP_OFF_BYTES 8192

// NCHW fp32 -> NHWC fp16: in[b][c][hw] -> out[b][hw][c]
__global__ __launch_bounds__(256) void transpose_h_k(const float* __restrict__ in,
                                                     _Float16* __restrict__ out) {
    __shared__ float tile[64][33];
    int b  = blockIdx.z;
    int c0 = blockIdx.y * 64;
    int s0 = blockIdx.x * 32;
    int lin = threadIdx.x;
    int tx  = lin & 31;
    int ty  = lin >> 5;

    const float* ip = in + ((size_t)(b * Cv + c0 + ty)) * HWv + s0 + tx;
#pragma unroll
    for (int i = 0; i < 64; i += 8)
        tile[ty + i][tx] = ip[(size_t)i * HWv];
    __syncthreads();

    int cp = lin & 31;
    int r8 = lin >> 5;
#pragma unroll
    for (int it = 0; it < 4; ++it) {
        int r = r8 + it * 8;
        union { _Float16 h[2]; unsigned u; } pk;
        pk.h[0] = (_Float16)tile[2 * cp + 0][r];
        pk.h[1] = (_Float16)tile[2 * cp + 1][r];
        unsigned* dst = (unsigned*)(out + ((size_t)b * HWv + s0 + r) * Cv + c0);
        dst[cp] = pk.u;
    }
}

// Counting-sort the 1024 g-rows by batch id; emit perm/cnt/off and the
// cumulative block counts for the (batch-major, half-major) dispatch order.
__global__ __launch_bounds__(1024) void prep_k(const int* __restrict__ bids,
                                               int* __restrict__ meta) {
    __shared__ int hist[8], base[8];
    int t = threadIdx.x;
    if (t < 8) hist[t] = 0;
    __syncthreads();
    int b = bids[t] & 7;
    int rank = atomicAdd(&hist[b], 1);
    __syncthreads();
    if (t == 0) {
        int acc = 0;
#pragma unroll
        for (int j = 0; j < 8; ++j) { base[j] = acc; acc += hist[j]; }
        int blk = 0;
#pragma unroll
        for (int j = 0; j <= 8; ++j) {
            meta[1040 + j] = blk;                 // cum[j] in blocks
            if (j < 8) blk += hist[j] * 256;      // 2 halves * 128 chunks per g
        }
    }
    __syncthreads();
    meta[base[b] + rank] = t;                     // perm
    if (t < 8) {
        meta[1024 + t] = hist[t];                 // cnt
        meta[1032 + t] = base[t];                 // off
    }
}

// Blocks dispatched in (batch, half, g, chunk)-major order: each XCD's L2
// sees one 4.2 MB (batch, channel-half) partition at a time.
// Block = 256 threads = 8 points x 128 channels (one half).
__global__ __launch_bounds__(256) void sample_loc_k(const _Float16* __restrict__ map,
                                                    const float* __restrict__ pts,
                                                    const int* __restrict__ meta,
                                                    float* __restrict__ out) {
    const int* perm = meta;
    const int* cnt  = meta + 1024;
    const int* off  = meta + 1032;
    const int* cum  = meta + 1040;

    int s = blockIdx.x;
    int j = 0;
#pragma unroll
    for (int k = 1; k < 8; ++k) j += (s >= cum[k]) ? 1 : 0;
    int r = s - cum[j];
    int W = cnt[j] << 7;                  // blocks per half for this batch
    int h = (r >= W) ? 1 : 0;
    r -= h * W;
    int gi = r >> 7, chunk = r & 127;
    int g = perm[off[j] + gi];

    int t    = threadIdx.x;
    int wv   = t >> 6;
    int lane = t & 63;
    int hl   = lane & 31;                 // channel-quad within the half
    int which = lane >> 5;                // which of the wave's 2 points
    int pt = (g << 10) + (chunk << 3) + (wv << 1) + which;

    float px = pts[2 * (size_t)pt + 0];
    float py = pts[2 * (size_t)pt + 1];

    float x = (float)Wv * px - 0.5f;
    float y = (float)Hv * py - 0.5f;
    float x0f = floorf(x), y0f = floorf(y);
    float wx = x - x0f, wy = y - y0f;
    int x0 = (int)x0f, y0 = (int)y0f;
    int x1 = x0 + 1,   y1 = y0 + 1;

    bool vx0 = (unsigned)x0 < (unsigned)Wv;
    bool vx1 = (unsigned)x1 < (unsigned)Wv;
    bool vy0 = (unsigned)y0 < (unsigned)Hv;
    bool vy1 = (unsigned)y1 < (unsigned)Hv;
    int xc0 = min(max(x0, 0), Wv - 1);
    int xc1 = min(max(x1, 0), Wv - 1);
    int yc0 = min(max(y0, 0), Hv - 1);
    int yc1 = min(max(y1, 0), Hv - 1);

    float w00 = (1.0f - wx) * (1.0f - wy) * ((vx0 & vy0) ? 1.0f : 0.0f);
    float w01 = wx * (1.0f - wy)          * ((vx1 & vy0) ? 1.0f : 0.0f);
    float w10 = (1.0f - wx) * wy          * ((vx0 & vy1) ? 1.0f : 0.0f);
    float w11 = wx * wy                   * ((vx1 & vy1) ? 1.0f : 0.0f);

    size_t bbase = (size_t)j * HWv * Cv;
    size_t o00 = bbase + ((size_t)yc0 * Wv + xc0) * Cv;
    size_t o01 = bbase + ((size_t)yc0 * Wv + xc1) * Cv;
    size_t o10 = bbase + ((size_t)yc1 * Wv + xc0) * Cv;
    size_t o11 = bbase + ((size_t)yc1 * Wv + xc1) * Cv;

    int c0 = (h << 7) + (hl << 2);        // channel offset of this lane's quad

    half4 v00 = *(const half4*)(map + o00 + c0);
    half4 v01 = *(const half4*)(map + o01 + c0);
    half4 v10 = *(const half4*)(map + o10 + c0);
    half4 v11 = *(const half4*)(map + o11 + c0);

    f32x4 rr;
    rr.x = (float)v00.x * w00 + (float)v01.x * w01 + (float)v10.x * w10 + (float)v11.x * w11;
    rr.y = (float)v00.y * w00 + (float)v01.y * w01 + (float)v10.y * w10 + (float)v11.y * w11;
    rr.z = (float)v00.z * w00 + (float)v01.z * w01 + (float)v10.z * w10 + (float)v11.z * w11;
    rr.w = (float)v00.w * w00 + (float)v01.w * w01 + (float)v10.w * w10 + (float)v11.w * w11;

    __builtin_nontemporal_store(rr, (f32x4*)(out + (size_t)pt * Cv + c0));
}

// Fallback: direct NCHW fp32 gather (correctness-only path, tiny ws).
__global__ __launch_bounds__(256) void sample_nchw_k(const float* __restrict__ map,
                                                     const float* __restrict__ pts,
                                                     const int* __restrict__ bids,
                                                     float* __restrict__ out) {
    int t    = blockIdx.x * 256 + threadIdx.x;
    int pt   = t >> 6;
    int lane = t & 63;

    int g = pt >> 10;
    float px = pts[2 * (size_t)pt + 0];
    float py = pts[2 * (size_t)pt + 1];
    int b = bids[g];
    float x = (float)Wv * px - 0.5f;
    float y = (float)Hv * py - 0.5f;
    float x0f = floorf(x), y0f = floorf(y);
    float wx = x - x0f, wy = y - y0f;
    int x0 = (int)x0f, y0 = (int)y0f;
    int x1 = x0 + 1,   y1 = y0 + 1;
    bool vx0 = (unsigned)x0 < (unsigned)Wv;
    bool vx1 = (unsigned)x1 < (unsigned)Wv;
    bool vy0 = (unsigned)y0 < (unsigned)Hv;
    bool vy1 = (unsigned)y1 < (unsigned)Hv;
    int xc0 = min(max(x0, 0), Wv - 1);
    int xc1 = min(max(x1, 0), Wv - 1);
    int yc0 = min(max(y0, 0), Hv - 1);
    int yc1 = min(max(y1, 0), Hv - 1);
    float w00 = (1.0f - wx) * (1.0f - wy) * ((vx0 & vy0) ? 1.0f : 0.0f);
    float w01 = wx * (1.0f - wy)          * ((vx1 & vy0) ? 1.0f : 0.0f);
    float w10 = (1.0f - wx) * wy          * ((vx0 & vy1) ? 1.0f : 0.0f);
    float w11 = wx * wy                   * ((vx1 & vy1) ? 1.0f : 0.0f);

    int c = lane * 4;
    const float* base = map + ((size_t)b * Cv + c) * HWv;
    size_t s00 = (size_t)yc0 * Wv + xc0;
    size_t s01 = (size_t)yc0 * Wv + xc1;
    size_t s10 = (size_t)yc1 * Wv + xc0;
    size_t s11 = (size_t)yc1 * Wv + xc1;

    f32x4 r;
#pragma unroll
    for (int jj = 0; jj < 4; ++jj) {
        const float* ch = base + (size_t)jj * HWv;
        r[jj] = ch[s00] * w00 + ch[s01] * w01 + ch[s10] * w10 + ch[s11] * w11;
    }
    *((f32x4*)(out + (size_t)pt * Cv) + lane) = r;
}

extern "C" void kernel_launch(void* const* d_in, const int* in_sizes, int n_in,
                              void* d_out, int out_size, void* d_ws, size_t ws_size,
                              hipStream_t stream) {
    const float* map  = (const float*)d_in[0];
    const float* pts  = (const float*)d_in[1];
    const int*   bids = (const int*)d_in[2];
    float*       out  = (float*)d_out;

    size_t need = MAP_OFF_BYTES + (size_t)Bv * HWv * Cv * sizeof(_Float16);
    int npts = Gv * Pv;

    if (ws_size >= need) {
        int*      meta = (int*)d_ws;
        _Float16* nhwc = (_Float16*)((char*)d_ws + MAP_OFF_BYTES);

        prep_k<<<1, 1024, 0, stream>>>(bids, meta);
        transpose_h_k<<<dim3(HWv / 32, Cv / 64, Bv), 256, 0, stream>>>(map, nhwc);

        // total useful blocks = sum_j 256 * n_j = 256 * 1024 (independent of bids)
        int nblocks = 256 * Gv;
        sample_loc_k<<<nblocks, 256, 0, stream>>>(nhwc, pts, meta, out);
    } else {
        int nblocks = npts * 64 / 256;
        sample_nchw_k<<<nblocks, 256, 0, stream>>>(map, pts, bids, out);
    }
}

// Round 5
// 284.563 us; speedup vs baseline: 2.6798x; 1.0787x over previous
//
#include <hip/hip_runtime.h>

#define Bv 8
#define Cv 256
#define Hv 128
#define Wv 128
#define HWv (Hv * Wv)
#define Gv 1024
#define Pv 1024
#define NBLK (256 * Gv)          // total sampler blocks = total work items
#define SLOTS (NBLK / 8)         // blocks per residue class

typedef __attribute__((ext_vector_type(4))) _Float16 half4;
typedef __attribute__((ext_vector_type(4))) float f32x4;

// d_ws layout:
//   [0, 8K)   : meta ints: perm[1024] | cnt[8]@1024 | off[8]@1032 | W[8]@1040
//                          | PL[8]@1048 | PE[8]@1056
//   [8K, ...) : fp16 NHWC map (B*HW*C halves = 67 MB)
#define MAP_OFF_BYTES 8192

// NCHW fp32 -> NHWC fp16: in[b][c][hw] -> out[b][hw][c]
__global__ __launch_bounds__(256) void transpose_h_k(const float* __restrict__ in,
                                                     _Float16* __restrict__ out) {
    __shared__ float tile[64][33];
    int b  = blockIdx.z;
    int c0 = blockIdx.y * 64;
    int s0 = blockIdx.x * 32;
    int lin = threadIdx.x;
    int tx  = lin & 31;
    int ty  = lin >> 5;

    const float* ip = in + ((size_t)(b * Cv + c0 + ty)) * HWv + s0 + tx;
#pragma unroll
    for (int i = 0; i < 64; i += 8)
        tile[ty + i][tx] = ip[(size_t)i * HWv];
    __syncthreads();

    int cp = lin & 31;
    int r8 = lin >> 5;
#pragma unroll
    for (int it = 0; it < 4; ++it) {
        int r = r8 + it * 8;
        union { _Float16 h[2]; unsigned u; } pk;
        pk.h[0] = (_Float16)tile[2 * cp + 0][r];
        pk.h[1] = (_Float16)tile[2 * cp + 1][r];
        unsigned* dst = (unsigned*)(out + ((size_t)b * HWv + s0 + r) * Cv + c0);
        dst[cp] = pk.u;
    }
}

// Counting-sort g-rows by batch id + residue/slot matching prefix sums.
__global__ __launch_bounds__(1024) void prep_k(const int* __restrict__ bids,
                                               int* __restrict__ meta) {
    __shared__ int hist[8], base[8];
    int t = threadIdx.x;
    if (t < 8) hist[t] = 0;
    __syncthreads();
    int b = bids[t] & 7;
    int rank = atomicAdd(&hist[b], 1);
    __syncthreads();
    if (t == 0) {
        int acc = 0;
#pragma unroll
        for (int j = 0; j < 8; ++j) { base[j] = acc; acc += hist[j]; }
        int pl = 0, pe = 0;
#pragma unroll
        for (int j = 0; j < 8; ++j) {
            int W = hist[j] * 256;            // items for batch j (2 halves x 128 chunks)
            meta[1024 + j] = hist[j];
            meta[1032 + j] = base[j];
            meta[1040 + j] = W;
            meta[1048 + j] = pl;              // prefix of spare block slots
            meta[1056 + j] = pe;              // prefix of excess items
            pl += max(0, SLOTS - W);
            pe += max(0, W - SLOTS);
        }
    }
    __syncthreads();
    meta[base[b] + rank] = t;                 // perm
}

// Block = 256 threads = 8 points x 128 channels (one half of C).
// Residue class (blockIdx % 8) owns batch (residue): under round-robin
// block->XCD dispatch each XCD's L2 only ever holds ONE batch's map half.
// Spare slots of under-full residues deterministically pick up excess items
// of over-full batches (correct under any block->XCD mapping).
__global__ __launch_bounds__(256) void sample_xcd_k(const _Float16* __restrict__ map,
                                                    const float* __restrict__ pts,
                                                    const int* __restrict__ meta,
                                                    float* __restrict__ out) {
    const int* perm = meta;
    const int* cnt  = meta + 1024;
    const int* off  = meta + 1032;
    const int* Wq   = meta + 1040;
    const int* PL   = meta + 1048;
    const int* PE   = meta + 1056;

    int bid = blockIdx.x;
    int k = bid & 7;
    int s = bid >> 3;

    int j, i;
    int Wk = Wq[k];
    if (s < Wk) {
        j = k; i = s;                         // own batch, in-order (windowed halves)
    } else {
        int r = PL[k] + (s - Wk);             // global spare rank
        j = 0;
#pragma unroll
        for (int q = 1; q < 8; ++q) j += (r >= PE[q]) ? 1 : 0;
        i = SLOTS + (r - PE[j]);              // excess item of batch j
    }

    int half_items = cnt[j] << 7;             // cnt*128 chunks per half
    int h  = (i >= half_items) ? 1 : 0;
    int rr = i - h * half_items;
    int gi = rr >> 7, chunk = rr & 127;
    int g  = perm[off[j] + gi];

    int t    = threadIdx.x;
    int wv   = t >> 6;
    int lane = t & 63;
    int hl   = lane & 31;                     // channel-quad within the half
    int which = lane >> 5;                    // which of the wave's 2 points
    int pt = (g << 10) + (chunk << 3) + (wv << 1) + which;

    float px = pts[2 * (size_t)pt + 0];
    float py = pts[2 * (size_t)pt + 1];

    float x = (float)Wv * px - 0.5f;
    float y = (float)Hv * py - 0.5f;
    float x0f = floorf(x), y0f = floorf(y);
    float wx = x - x0f, wy = y - y0f;
    int x0 = (int)x0f, y0 = (int)y0f;
    int x1 = x0 + 1,   y1 = y0 + 1;

    bool vx0 = (unsigned)x0 < (unsigned)Wv;
    bool vx1 = (unsigned)x1 < (unsigned)Wv;
    bool vy0 = (unsigned)y0 < (unsigned)Hv;
    bool vy1 = (unsigned)y1 < (unsigned)Hv;
    int xc0 = min(max(x0, 0), Wv - 1);
    int xc1 = min(max(x1, 0), Wv - 1);
    int yc0 = min(max(y0, 0), Hv - 1);
    int yc1 = min(max(y1, 0), Hv - 1);

    float w00 = (1.0f - wx) * (1.0f - wy) * ((vx0 & vy0) ? 1.0f : 0.0f);
    float w01 = wx * (1.0f - wy)          * ((vx1 & vy0) ? 1.0f : 0.0f);
    float w10 = (1.0f - wx) * wy          * ((vx0 & vy1) ? 1.0f : 0.0f);
    float w11 = wx * wy                   * ((vx1 & vy1) ? 1.0f : 0.0f);

    size_t bbase = (size_t)j * HWv * Cv;
    size_t o00 = bbase + ((size_t)yc0 * Wv + xc0) * Cv;
    size_t o01 = bbase + ((size_t)yc0 * Wv + xc1) * Cv;
    size_t o10 = bbase + ((size_t)yc1 * Wv + xc0) * Cv;
    size_t o11 = bbase + ((size_t)yc1 * Wv + xc1) * Cv;

    int c0 = (h << 7) + (hl << 2);

    half4 v00 = *(const half4*)(map + o00 + c0);
    half4 v01 = *(const half4*)(map + o01 + c0);
    half4 v10 = *(const half4*)(map + o10 + c0);
    half4 v11 = *(const half4*)(map + o11 + c0);

    f32x4 rr2;
    rr2.x = (float)v00.x * w00 + (float)v01.x * w01 + (float)v10.x * w10 + (float)v11.x * w11;
    rr2.y = (float)v00.y * w00 + (float)v01.y * w01 + (float)v10.y * w10 + (float)v11.y * w11;
    rr2.z = (float)v00.z * w00 + (float)v01.z * w01 + (float)v10.z * w10 + (float)v11.z * w11;
    rr2.w = (float)v00.w * w00 + (float)v01.w * w01 + (float)v10.w * w10 + (float)v11.w * w11;

    __builtin_nontemporal_store(rr2, (f32x4*)(out + (size_t)pt * Cv + c0));
}

// Fallback: direct NCHW fp32 gather (correctness-only path, tiny ws).
__global__ __launch_bounds__(256) void sample_nchw_k(const float* __restrict__ map,
                                                     const float* __restrict__ pts,
                                                     const int* __restrict__ bids,
                                                     float* __restrict__ out) {
    int t    = blockIdx.x * 256 + threadIdx.x;
    int pt   = t >> 6;
    int lane = t & 63;

    int g = pt >> 10;
    float px = pts[2 * (size_t)pt + 0];
    float py = pts[2 * (size_t)pt + 1];
    int b = bids[g];
    float x = (float)Wv * px - 0.5f;
    float y = (float)Hv * py - 0.5f;
    float x0f = floorf(x), y0f = floorf(y);
    float wx = x - x0f, wy = y - y0f;
    int x0 = (int)x0f, y0 = (int)y0f;
    int x1 = x0 + 1,   y1 = y0 + 1;
    bool vx0 = (unsigned)x0 < (unsigned)Wv;
    bool vx1 = (unsigned)x1 < (unsigned)Wv;
    bool vy0 = (unsigned)y0 < (unsigned)Hv;
    bool vy1 = (unsigned)y1 < (unsigned)Hv;
    int xc0 = min(max(x0, 0), Wv - 1);
    int xc1 = min(max(x1, 0), Wv - 1);
    int yc0 = min(max(y0, 0), Hv - 1);
    int yc1 = min(max(y1, 0), Hv - 1);
    float w00 = (1.0f - wx) * (1.0f - wy) * ((vx0 & vy0) ? 1.0f : 0.0f);
    float w01 = wx * (1.0f - wy)          * ((vx1 & vy0) ? 1.0f : 0.0f);
    float w10 = (1.0f - wx) * wy          * ((vx0 & vy1) ? 1.0f : 0.0f);
    float w11 = wx * wy                   * ((vx1 & vy1) ? 1.0f : 0.0f);

    int c = lane * 4;
    const float* base = map + ((size_t)b * Cv + c) * HWv;
    size_t s00 = (size_t)yc0 * Wv + xc0;
    size_t s01 = (size_t)yc0 * Wv + xc1;
    size_t s10 = (size_t)yc1 * Wv + xc0;
    size_t s11 = (size_t)yc1 * Wv + xc1;

    f32x4 r;
#pragma unroll
    for (int jj = 0; jj < 4; ++jj) {
        const float* ch = base + (size_t)jj * HWv;
        r[jj] = ch[s00] * w00 + ch[s01] * w01 + ch[s10] * w10 + ch[s11] * w11;
    }
    *((f32x4*)(out + (size_t)pt * Cv) + lane) = r;
}

extern "C" void kernel_launch(void* const* d_in, const int* in_sizes, int n_in,
                              void* d_out, int out_size, void* d_ws, size_t ws_size,
                              hipStream_t stream) {
    const float* map  = (const float*)d_in[0];
    const float* pts  = (const float*)d_in[1];
    const int*   bids = (const int*)d_in[2];
    float*       out  = (float*)d_out;

    size_t need = MAP_OFF_BYTES + (size_t)Bv * HWv * Cv * sizeof(_Float16);
    int npts = Gv * Pv;

    if (ws_size >= need) {
        int*      meta = (int*)d_ws;
        _Float16* nhwc = (_Float16*)((char*)d_ws + MAP_OFF_BYTES);

        prep_k<<<1, 1024, 0, stream>>>(bids, meta);
        transpose_h_k<<<dim3(HWv / 32, Cv / 64, Bv), 256, 0, stream>>>(map, nhwc);
        sample_xcd_k<<<NBLK, 256, 0, stream>>>(nhwc, pts, meta, out);
    } else {
        int nblocks = npts * 64 / 256;
        sample_nchw_k<<<nblocks, 256, 0, stream>>>(map, pts, bids, out);
    }
}

// Round 6
// 252.313 us; speedup vs baseline: 3.0223x; 1.1278x over previous
//
#include <hip/hip_runtime.h>

#define Bv 8
#define Cv 256
#define Hv 128
#define Wv 128
#define HWv (Hv * Wv)
#define Gv 1024
#define Pv 1024
#define NBLK (128 * Gv)          // sampler blocks: items = (batch, half, g, chunk-pair)
#define SLOTS (NBLK / 8)         // blocks per residue class (16384)

typedef __attribute__((ext_vector_type(4))) _Float16 half4;
typedef __attribute__((ext_vector_type(4))) float f32x4;
typedef __attribute__((ext_vector_type(4))) unsigned u32x4;

// d_ws layout:
//   [0, 8K)   : meta ints: perm[1024] | cnt[8]@1024 | off[8]@1032 | W[8]@1040
//                          | PL[8]@1048 (prefix spare slots) | PE[8]@1056 (prefix excess)
//   [8K, ...) : fp16 NHWC map (B*HW*C halves = 67 MB)
#define MAP_OFF_BYTES 8192

// Fused: z<8 -> NCHW fp32 -> NHWC fp16 transpose; z==8,(0,0) -> scheduling prep.
__global__ __launch_bounds__(256) void transpose_prep_k(const float* __restrict__ in,
                                                        _Float16* __restrict__ out,
                                                        const int* __restrict__ bids,
                                                        int* __restrict__ meta) {
    if (blockIdx.z == 8) {
        if (blockIdx.x != 0 || blockIdx.y != 0) return;
        __shared__ int hist[8], base[8];
        int t = threadIdx.x;
        if (t < 8) hist[t] = 0;
        __syncthreads();
        int rk[4], bb[4];
#pragma unroll
        for (int it = 0; it < 4; ++it) {
            int g = t + it * 256;
            int b = bids[g] & 7;
            bb[it] = b;
            rk[it] = atomicAdd(&hist[b], 1);
        }
        __syncthreads();
        if (t == 0) {
            int acc = 0;
#pragma unroll
            for (int j = 0; j < 8; ++j) { base[j] = acc; acc += hist[j]; }
            int pl = 0, pe = 0;
#pragma unroll
            for (int j = 0; j < 8; ++j) {
                int W = hist[j] * 128;        // chunk-pair items (2 halves x 64 pairs per g)
                meta[1024 + j] = hist[j];
                meta[1032 + j] = base[j];
                meta[1040 + j] = W;
                meta[1048 + j] = pl;
                meta[1056 + j] = pe;
                pl += max(0, SLOTS - W);
                pe += max(0, W - SLOTS);
            }
        }
        __syncthreads();
#pragma unroll
        for (int it = 0; it < 4; ++it)
            meta[base[bb[it]] + rk[it]] = t + it * 256;
        return;
    }

    __shared__ float tile[64][33];
    int b  = blockIdx.z;
    int c0 = blockIdx.y * 64;
    int s0 = blockIdx.x * 32;
    int lin = threadIdx.x;
    int tx  = lin & 31;
    int ty  = lin >> 5;

    const float* ip = in + ((size_t)(b * Cv + c0 + ty)) * HWv + s0 + tx;
#pragma unroll
    for (int i = 0; i < 64; i += 8)
        tile[ty + i][tx] = ip[(size_t)i * HWv];
    __syncthreads();

    // write phase: thread -> row r = lin>>3 (0..31), channel octet q = lin&7.
    // LDS banks: (8q+k + r) mod 32 -> 2-way max (free). 16B stores.
    int r = lin >> 3;
    int q = lin & 7;
    union { _Float16 h[8]; u32x4 v; } pk;
#pragma unroll
    for (int k = 0; k < 8; ++k)
        pk.h[k] = (_Float16)tile[8 * q + k][r];
    u32x4* dst = (u32x4*)(out + ((size_t)b * HWv + s0 + r) * Cv + c0 + 8 * q);
    *dst = pk.v;
}

__device__ __forceinline__ void point_setup_i(const float* __restrict__ pts, int pt, int bbase,
                                              int& o00, int& o01, int& o10, int& o11,
                                              float& w00, float& w01, float& w10, float& w11) {
    float px = pts[2 * (size_t)pt + 0];
    float py = pts[2 * (size_t)pt + 1];

    float x = (float)Wv * px - 0.5f;
    float y = (float)Hv * py - 0.5f;
    float x0f = floorf(x), y0f = floorf(y);
    float wx = x - x0f, wy = y - y0f;
    int x0 = (int)x0f, y0 = (int)y0f;
    int x1 = x0 + 1,   y1 = y0 + 1;

    bool vx0 = (unsigned)x0 < (unsigned)Wv;
    bool vx1 = (unsigned)x1 < (unsigned)Wv;
    bool vy0 = (unsigned)y0 < (unsigned)Hv;
    bool vy1 = (unsigned)y1 < (unsigned)Hv;
    int xc0 = min(max(x0, 0), Wv - 1);
    int xc1 = min(max(x1, 0), Wv - 1);
    int yc0 = min(max(y0, 0), Hv - 1);
    int yc1 = min(max(y1, 0), Hv - 1);

    w00 = (1.0f - wx) * (1.0f - wy) * ((vx0 & vy0) ? 1.0f : 0.0f);
    w01 = wx * (1.0f - wy)          * ((vx1 & vy0) ? 1.0f : 0.0f);
    w10 = (1.0f - wx) * wy          * ((vx0 & vy1) ? 1.0f : 0.0f);
    w11 = wx * wy                   * ((vx1 & vy1) ? 1.0f : 0.0f);

    o00 = bbase + (yc0 * Wv + xc0) * Cv;
    o01 = bbase + (yc0 * Wv + xc1) * Cv;
    o10 = bbase + (yc1 * Wv + xc0) * Cv;
    o11 = bbase + (yc1 * Wv + xc1) * Cv;
}

// Block = 256 threads = 16 points (chunk-pair) x 128 channels (one half of C).
// Residue class (blockIdx%8) owns batch (residue) under round-robin XCD dispatch.
// Foreign (excess) items are taken by the EARLIEST spare slots (cold-L2 period);
// the tail of each residue class is pure own-batch work.
__global__ __launch_bounds__(256) void sample_xcd_k(const _Float16* __restrict__ map,
                                                    const float* __restrict__ pts,
                                                    const int* __restrict__ meta,
                                                    float* __restrict__ out) {
    const int* perm = meta;
    const int* off  = meta + 1032;
    const int* Wq   = meta + 1040;
    const int* PL   = meta + 1048;
    const int* PE   = meta + 1056;

    int bid = blockIdx.x;
    int k = bid & 7;
    int s = bid >> 3;

    int Wk = Wq[k];
    int Lk = max(0, SLOTS - Wk);              // spare slots in this residue
    int j, i;
    if (s < Lk) {                             // foreign excess item (early, cold L2)
        int r = PL[k] + s;
        j = 0;
#pragma unroll
        for (int q = 1; q < 8; ++q) j += (r >= PE[q]) ? 1 : 0;
        i = SLOTS + (r - PE[j]);
    } else {                                  // own batch, in-order
        j = k;
        i = s - Lk;
    }

    int half_items = Wq[j] >> 1;              // cnt*64 chunk-pairs per half
    int h  = (i >= half_items) ? 1 : 0;
    int r2 = i - h * half_items;
    int gi = r2 >> 6, cp = r2 & 63;
    int g  = perm[off[j] + gi];

    int t    = threadIdx.x;
    int wv   = t >> 6;
    int lane = t & 63;
    int hl   = lane & 31;
    int which = lane >> 5;
    int ptA = (g << 10) + (cp << 4) + (wv << 1) + which;
    int ptB = ptA + 8;

    int bbase = j * (HWv * Cv);
    int a00, a01, a10, a11, b00, b01, b10, b11;
    float wa00, wa01, wa10, wa11, wb00, wb01, wb10, wb11;
    point_setup_i(pts, ptA, bbase, a00, a01, a10, a11, wa00, wa01, wa10, wa11);
    point_setup_i(pts, ptB, bbase, b00, b01, b10, b11, wb00, wb01, wb10, wb11);

    int c0 = (h << 7) + (hl << 2);

    half4 va00 = *(const half4*)(map + a00 + c0);
    half4 va01 = *(const half4*)(map + a01 + c0);
    half4 va10 = *(const half4*)(map + a10 + c0);
    half4 va11 = *(const half4*)(map + a11 + c0);
    half4 vb00 = *(const half4*)(map + b00 + c0);
    half4 vb01 = *(const half4*)(map + b01 + c0);
    half4 vb10 = *(const half4*)(map + b10 + c0);
    half4 vb11 = *(const half4*)(map + b11 + c0);

    f32x4 rA, rB;
    rA.x = (float)va00.x * wa00 + (float)va01.x * wa01 + (float)va10.x * wa10 + (float)va11.x * wa11;
    rA.y = (float)va00.y * wa00 + (float)va01.y * wa01 + (float)va10.y * wa10 + (float)va11.y * wa11;
    rA.z = (float)va00.z * wa00 + (float)va01.z * wa01 + (float)va10.z * wa10 + (float)va11.z * wa11;
    rA.w = (float)va00.w * wa00 + (float)va01.w * wa01 + (float)va10.w * wa10 + (float)va11.w * wa11;
    rB.x = (float)vb00.x * wb00 + (float)vb01.x * wb01 + (float)vb10.x * wb10 + (float)vb11.x * wb11;
    rB.y = (float)vb00.y * wb00 + (float)vb01.y * wb01 + (float)vb10.y * wb10 + (float)vb11.y * wb11;
    rB.z = (float)vb00.z * wb00 + (float)vb01.z * wb01 + (float)vb10.z * wb10 + (float)vb11.z * wb11;
    rB.w = (float)vb00.w * wb00 + (float)vb01.w * wb01 + (float)vb10.w * wb10 + (float)vb11.w * wb11;

    __builtin_nontemporal_store(rA, (f32x4*)(out + (size_t)ptA * Cv + c0));
    __builtin_nontemporal_store(rB, (f32x4*)(out + (size_t)ptB * Cv + c0));
}

// Fallback: direct NCHW fp32 gather (correctness-only path, tiny ws).
__global__ __launch_bounds__(256) void sample_nchw_k(const float* __restrict__ map,
                                                     const float* __restrict__ pts,
                                                     const int* __restrict__ bids,
                                                     float* __restrict__ out) {
    int t    = blockIdx.x * 256 + threadIdx.x;
    int pt   = t >> 6;
    int lane = t & 63;

    int g = pt >> 10;
    float px = pts[2 * (size_t)pt + 0];
    float py = pts[2 * (size_t)pt + 1];
    int b = bids[g];
    float x = (float)Wv * px - 0.5f;
    float y = (float)Hv * py - 0.5f;
    float x0f = floorf(x), y0f = floorf(y);
    float wx = x - x0f, wy = y - y0f;
    int x0 = (int)x0f, y0 = (int)y0f;
    int x1 = x0 + 1,   y1 = y0 + 1;
    bool vx0 = (unsigned)x0 < (unsigned)Wv;
    bool vx1 = (unsigned)x1 < (unsigned)Wv;
    bool vy0 = (unsigned)y0 < (unsigned)Hv;
    bool vy1 = (unsigned)y1 < (unsigned)Hv;
    int xc0 = min(max(x0, 0), Wv - 1);
    int xc1 = min(max(x1, 0), Wv - 1);
    int yc0 = min(max(y0, 0), Hv - 1);
    int yc1 = min(max(y1, 0), Hv - 1);
    float w00 = (1.0f - wx) * (1.0f - wy) * ((vx0 & vy0) ? 1.0f : 0.0f);
    float w01 = wx * (1.0f - wy)          * ((vx1 & vy0) ? 1.0f : 0.0f);
    float w10 = (1.0f - wx) * wy          * ((vx0 & vy1) ? 1.0f : 0.0f);
    float w11 = wx * wy                   * ((vx1 & vy1) ? 1.0f : 0.0f);

    int c = lane * 4;
    const float* base = map + ((size_t)b * Cv + c) * HWv;
    size_t s00 = (size_t)yc0 * Wv + xc0;
    size_t s01 = (size_t)yc0 * Wv + xc1;
    size_t s10 = (size_t)yc1 * Wv + xc0;
    size_t s11 = (size_t)yc1 * Wv + xc1;

    f32x4 r;
#pragma unroll
    for (int jj = 0; jj < 4; ++jj) {
        const float* ch = base + (size_t)jj * HWv;
        r[jj] = ch[s00] * w00 + ch[s01] * w01 + ch[s10] * w10 + ch[s11] * w11;
    }
    *((f32x4*)(out + (size_t)pt * Cv) + lane) = r;
}

extern "C" void kernel_launch(void* const* d_in, const int* in_sizes, int n_in,
                              void* d_out, int out_size, void* d_ws, size_t ws_size,
                              hipStream_t stream) {
    const float* map  = (const float*)d_in[0];
    const float* pts  = (const float*)d_in[1];
    const int*   bids = (const int*)d_in[2];
    float*       out  = (float*)d_out;

    size_t need = MAP_OFF_BYTES + (size_t)Bv * HWv * Cv * sizeof(_Float16);
    int npts = Gv * Pv;

    if (ws_size >= need) {
        int*      meta = (int*)d_ws;
        _Float16* nhwc = (_Float16*)((char*)d_ws + MAP_OFF_BYTES);

        // z==8 plane carries the scheduling prep (1 useful block, concurrent).
        transpose_prep_k<<<dim3(HWv / 32, Cv / 64, Bv + 1), 256, 0, stream>>>(map, nhwc, bids, meta);
        sample_xcd_k<<<NBLK, 256, 0, stream>>>(nhwc, pts, meta, out);
    } else {
        int nblocks = npts * 64 / 256;
        sample_nchw_k<<<nblocks, 256, 0, stream>>>(map, pts, bids, out);
    }
}

// Round 7
// 250.188 us; speedup vs baseline: 3.0480x; 1.0085x over previous
//
#include <hip/hip_runtime.h>

#define Bv 8
#define Cv 256
#define Hv 128
#define Wv 128
#define HWv (Hv * Wv)
#define Gv 1024
#define Pv 1024
#define NBLK (64 * Gv)           // sampler blocks: items = (batch, half, g, chunk-quad)
#define SLOTS (NBLK / 8)         // blocks per residue class (8192)

typedef __attribute__((ext_vector_type(4))) _Float16 half4;
typedef __attribute__((ext_vector_type(4))) float f32x4;
typedef __attribute__((ext_vector_type(2))) float f32x2;
typedef __attribute__((ext_vector_type(4))) unsigned u32x4;

// d_ws layout:
//   [0, 8K)   : meta ints: perm[1024] | cnt[8]@1024 | off[8]@1032 | W[8]@1040
//                          | PL[8]@1048 (prefix spare slots) | PE[8]@1056 (prefix excess)
//   [8K, ...) : fp16 NHWC map (B*HW*C halves = 67 MB)
#define MAP_OFF_BYTES 8192

// Fused: z<8 -> NCHW fp32 -> NHWC fp16 transpose; z==8,(0,0) -> scheduling prep.
__global__ __launch_bounds__(256) void transpose_prep_k(const float* __restrict__ in,
                                                        _Float16* __restrict__ out,
                                                        const int* __restrict__ bids,
                                                        int* __restrict__ meta) {
    if (blockIdx.z == 8) {
        if (blockIdx.x != 0 || blockIdx.y != 0) return;
        __shared__ int hist[8], base[8];
        int t = threadIdx.x;
        if (t < 8) hist[t] = 0;
        __syncthreads();
        int rk[4], bb[4];
#pragma unroll
        for (int it = 0; it < 4; ++it) {
            int g = t + it * 256;
            int b = bids[g] & 7;
            bb[it] = b;
            rk[it] = atomicAdd(&hist[b], 1);
        }
        __syncthreads();
        if (t == 0) {
            int acc = 0;
#pragma unroll
            for (int j = 0; j < 8; ++j) { base[j] = acc; acc += hist[j]; }
            int pl = 0, pe = 0;
#pragma unroll
            for (int j = 0; j < 8; ++j) {
                int W = hist[j] * 64;         // chunk-quad items (2 halves x 32 per g)
                meta[1024 + j] = hist[j];
                meta[1032 + j] = base[j];
                meta[1040 + j] = W;
                meta[1048 + j] = pl;
                meta[1056 + j] = pe;
                pl += max(0, SLOTS - W);
                pe += max(0, W - SLOTS);
            }
        }
        __syncthreads();
#pragma unroll
        for (int it = 0; it < 4; ++it)
            meta[base[bb[it]] + rk[it]] = t + it * 256;
        return;
    }

    __shared__ float tile[64][33];
    int b  = blockIdx.z;
    int c0 = blockIdx.y * 64;
    int s0 = blockIdx.x * 32;
    int lin = threadIdx.x;
    int tx  = lin & 31;
    int ty  = lin >> 5;

    const float* ip = in + ((size_t)(b * Cv + c0 + ty)) * HWv + s0 + tx;
#pragma unroll
    for (int i = 0; i < 64; i += 8)
        tile[ty + i][tx] = ip[(size_t)i * HWv];
    __syncthreads();

    // write phase: thread -> row r = lin>>3 (0..31), channel octet q = lin&7. 16B stores.
    int r = lin >> 3;
    int q = lin & 7;
    union { _Float16 h[8]; u32x4 v; } pk;
#pragma unroll
    for (int k = 0; k < 8; ++k)
        pk.h[k] = (_Float16)tile[8 * q + k][r];
    u32x4* dst = (u32x4*)(out + ((size_t)b * HWv + s0 + r) * Cv + c0 + 8 * q);
    *dst = pk.v;
}

__device__ __forceinline__ void point_setup_i(const float* __restrict__ pts, int pt, int bbase,
                                              int* o, float* w) {
    f32x2 p = *(const f32x2*)(pts + 2 * (size_t)pt);

    float x = (float)Wv * p.x - 0.5f;
    float y = (float)Hv * p.y - 0.5f;
    float x0f = floorf(x), y0f = floorf(y);
    float wx = x - x0f, wy = y - y0f;
    int x0 = (int)x0f, y0 = (int)y0f;
    int x1 = x0 + 1,   y1 = y0 + 1;

    bool vx0 = (unsigned)x0 < (unsigned)Wv;
    bool vx1 = (unsigned)x1 < (unsigned)Wv;
    bool vy0 = (unsigned)y0 < (unsigned)Hv;
    bool vy1 = (unsigned)y1 < (unsigned)Hv;
    int xc0 = min(max(x0, 0), Wv - 1);
    int xc1 = min(max(x1, 0), Wv - 1);
    int yc0 = min(max(y0, 0), Hv - 1);
    int yc1 = min(max(y1, 0), Hv - 1);

    w[0] = (1.0f - wx) * (1.0f - wy) * ((vx0 & vy0) ? 1.0f : 0.0f);
    w[1] = wx * (1.0f - wy)          * ((vx1 & vy0) ? 1.0f : 0.0f);
    w[2] = (1.0f - wx) * wy          * ((vx0 & vy1) ? 1.0f : 0.0f);
    w[3] = wx * wy                   * ((vx1 & vy1) ? 1.0f : 0.0f);

    o[0] = bbase + (yc0 * Wv + xc0) * Cv;
    o[1] = bbase + (yc0 * Wv + xc1) * Cv;
    o[2] = bbase + (yc1 * Wv + xc0) * Cv;
    o[3] = bbase + (yc1 * Wv + xc1) * Cv;
}

// Block = 256 threads = 32 points (chunk-quad) x 128 channels (one half of C).
// Each thread: 4 points x 4 channels -> 16 outstanding gathers (MLP).
// Residue class (blockIdx%8) owns batch (residue) under round-robin XCD dispatch;
// foreign (excess) items run in the EARLIEST spare slots (cold-L2 period).
__global__ __launch_bounds__(256) void sample_xcd_k(const _Float16* __restrict__ map,
                                                    const float* __restrict__ pts,
                                                    const int* __restrict__ meta,
                                                    float* __restrict__ out) {
    const int* perm = meta;
    const int* off  = meta + 1032;
    const int* Wq   = meta + 1040;
    const int* PL   = meta + 1048;
    const int* PE   = meta + 1056;

    int bid = blockIdx.x;
    int k = bid & 7;
    int s = bid >> 3;

    int Wk = Wq[k];
    int Lk = max(0, SLOTS - Wk);              // spare slots in this residue
    int j, i;
    if (s < Lk) {                             // foreign excess item (early, cold L2)
        int r = PL[k] + s;
        j = 0;
#pragma unroll
        for (int q = 1; q < 8; ++q) j += (r >= PE[q]) ? 1 : 0;
        i = SLOTS + (r - PE[j]);
    } else {                                  // own batch, in-order
        j = k;
        i = s - Lk;
    }

    int half_items = Wq[j] >> 1;              // cnt*32 chunk-quads per half
    int h  = (i >= half_items) ? 1 : 0;
    int r2 = i - h * half_items;
    int gi = r2 >> 5, cq = r2 & 31;
    int g  = perm[off[j] + gi];

    int t    = threadIdx.x;
    int lane = t & 63;
    int hl   = lane & 31;                     // channel-quad within the half
    int slot = ((t >> 6) << 1) + (lane >> 5); // 0..7
    int pbase = (g << 10) + (cq << 5) + slot; // points: pbase + 8*m, m=0..3

    int bbase = j * (HWv * Cv);
    int o[4][4];
    float w[4][4];
#pragma unroll
    for (int m = 0; m < 4; ++m)
        point_setup_i(pts, pbase + 8 * m, bbase, o[m], w[m]);

    int c0 = (h << 7) + (hl << 2);

    half4 v[4][4];
#pragma unroll
    for (int m = 0; m < 4; ++m)
#pragma unroll
        for (int c = 0; c < 4; ++c)
            v[m][c] = *(const half4*)(map + o[m][c] + c0);

#pragma unroll
    for (int m = 0; m < 4; ++m) {
        f32x4 r;
        r.x = (float)v[m][0].x * w[m][0] + (float)v[m][1].x * w[m][1] +
              (float)v[m][2].x * w[m][2] + (float)v[m][3].x * w[m][3];
        r.y = (float)v[m][0].y * w[m][0] + (float)v[m][1].y * w[m][1] +
              (float)v[m][2].y * w[m][2] + (float)v[m][3].y * w[m][3];
        r.z = (float)v[m][0].z * w[m][0] + (float)v[m][1].z * w[m][1] +
              (float)v[m][2].z * w[m][2] + (float)v[m][3].z * w[m][3];
        r.w = (float)v[m][0].w * w[m][0] + (float)v[m][1].w * w[m][1] +
              (float)v[m][2].w * w[m][2] + (float)v[m][3].w * w[m][3];
        __builtin_nontemporal_store(r, (f32x4*)(out + (size_t)(pbase + 8 * m) * Cv + c0));
    }
}

// Fallback: direct NCHW fp32 gather (correctness-only path, tiny ws).
__global__ __launch_bounds__(256) void sample_nchw_k(const float* __restrict__ map,
                                                     const float* __restrict__ pts,
                                                     const int* __restrict__ bids,
                                                     float* __restrict__ out) {
    int t    = blockIdx.x * 256 + threadIdx.x;
    int pt   = t >> 6;
    int lane = t & 63;

    int g = pt >> 10;
    float px = pts[2 * (size_t)pt + 0];
    float py = pts[2 * (size_t)pt + 1];
    int b = bids[g];
    float x = (float)Wv * px - 0.5f;
    float y = (float)Hv * py - 0.5f;
    float x0f = floorf(x), y0f = floorf(y);
    float wx = x - x0f, wy = y - y0f;
    int x0 = (int)x0f, y0 = (int)y0f;
    int x1 = x0 + 1,   y1 = y0 + 1;
    bool vx0 = (unsigned)x0 < (unsigned)Wv;
    bool vx1 = (unsigned)x1 < (unsigned)Wv;
    bool vy0 = (unsigned)y0 < (unsigned)Hv;
    bool vy1 = (unsigned)y1 < (unsigned)Hv;
    int xc0 = min(max(x0, 0), Wv - 1);
    int xc1 = min(max(x1, 0), Wv - 1);
    int yc0 = min(max(y0, 0), Hv - 1);
    int yc1 = min(max(y1, 0), Hv - 1);
    float w00 = (1.0f - wx) * (1.0f - wy) * ((vx0 & vy0) ? 1.0f : 0.0f);
    float w01 = wx * (1.0f - wy)          * ((vx1 & vy0) ? 1.0f : 0.0f);
    float w10 = (1.0f - wx) * wy          * ((vx0 & vy1) ? 1.0f : 0.0f);
    float w11 = wx * wy                   * ((vx1 & vy1) ? 1.0f : 0.0f);

    int c = lane * 4;
    const float* base = map + ((size_t)b * Cv + c) * HWv;
    size_t s00 = (size_t)yc0 * Wv + xc0;
    size_t s01 = (size_t)yc0 * Wv + xc1;
    size_t s10 = (size_t)yc1 * Wv + xc0;
    size_t s11 = (size_t)yc1 * Wv + xc1;

    f32x4 r;
#pragma unroll
    for (int jj = 0; jj < 4; ++jj) {
        const float* ch = base + (size_t)jj * HWv;
        r[jj] = ch[s00] * w00 + ch[s01] * w01 + ch[s10] * w10 + ch[s11] * w11;
    }
    *((f32x4*)(out + (size_t)pt * Cv) + lane) = r;
}

extern "C" void kernel_launch(void* const* d_in, const int* in_sizes, int n_in,
                              void* d_out, int out_size, void* d_ws, size_t ws_size,
                              hipStream_t stream) {
    const float* map  = (const float*)d_in[0];
    const float* pts  = (const float*)d_in[1];
    const int*   bids = (const int*)d_in[2];
    float*       out  = (float*)d_out;

    size_t need = MAP_OFF_BYTES + (size_t)Bv * HWv * Cv * sizeof(_Float16);
    int npts = Gv * Pv;

    if (ws_size >= need) {
        int*      meta = (int*)d_ws;
        _Float16* nhwc = (_Float16*)((char*)d_ws + MAP_OFF_BYTES);

        // z==8 plane carries the scheduling prep (1 useful block, concurrent).
        transpose_prep_k<<<dim3(HWv / 32, Cv / 64, Bv + 1), 256, 0, stream>>>(map, nhwc, bids, meta);
        sample_xcd_k<<<NBLK, 256, 0, stream>>>(nhwc, pts, meta, out);
    } else {
        int nblocks = npts * 64 / 256;
        sample_nchw_k<<<nblocks, 256, 0, stream>>>(map, pts, bids, out);
    }
}